// Round 3
// baseline (488.865 us; speedup 1.0000x reference)
//
#include <hip/hip_runtime.h>
#include <hip/hip_bf16.h>

#define ENC_DIM 2048
#define DEC_DIM 512
#define ATT_DIM 512
#define BATCH   256
#define NPIX    196
#define MROWS   (BATCH * NPIX)          // 50176 = 392 * 128
#define NTILES  64                      // K tiles of 32

typedef __attribute__((ext_vector_type(8)))  short short8;
typedef __attribute__((ext_vector_type(16))) float f32x16;

typedef const __attribute__((address_space(1))) unsigned int gu32;
typedef __attribute__((address_space(3))) unsigned int lu32;

__device__ __forceinline__ short f2bf(float x) {
    // round-to-nearest-even bf16 (inputs are finite normals)
    unsigned u = __builtin_bit_cast(unsigned, x);
    unsigned r = (u + 0x7FFFu + ((u >> 16) & 1u)) >> 16;
    return (short)r;
}

// ---------------------------------------------------------------------------
// prep: blocks [0,256)   -> att2pb[b][a] = b_enc[a] + b_dec[a] + h[b]·W_dec[:,a]
//       blocks [256,768) -> pack W_enc into bf16 MFMA B-fragment order
//                           (32x32x16): chunk c = (nt*128+kb16)*64+lane,
//                           elem j = W_enc[kb16*16+(lane>>5)*8+j][nt*32+(lane&31)]
// ---------------------------------------------------------------------------
__global__ __launch_bounds__(256) void bahdanau_prep(
    const float* __restrict__ dec_h, const float* __restrict__ W_enc,
    const float* __restrict__ b_enc, const float* __restrict__ W_dec,
    const float* __restrict__ b_dec,
    float* __restrict__ att2pb, short* __restrict__ Wpack)
{
    int blk = blockIdx.x;
    if (blk < BATCH) {
        __shared__ float hs[DEC_DIM];
        int b = blk;
        for (int i = threadIdx.x; i < DEC_DIM; i += 256) hs[i] = dec_h[b * DEC_DIM + i];
        __syncthreads();
        for (int a = threadIdx.x; a < ATT_DIM; a += 256) {
            float s = 0.f;
            #pragma unroll 8
            for (int d = 0; d < DEC_DIM; ++d) s += hs[d] * W_dec[d * ATT_DIM + a];
            att2pb[b * ATT_DIM + a] = s + b_dec[a] + b_enc[a];
        }
    } else {
        int c    = (blk - BATCH) * 256 + threadIdx.x;   // 0 .. 131071
        int lane = c & 63;
        int kb16 = (c >> 6) & 127;
        int nt   = c >> 13;
        int n     = nt * 32 + (lane & 31);
        int kbase = kb16 * 16 + (lane >> 5) * 8;
        short8 v;
        #pragma unroll
        for (int j = 0; j < 8; ++j) v[j] = f2bf(W_enc[(kbase + j) * ATT_DIM + n]);
        *reinterpret_cast<short8*>(Wpack + (size_t)c * 8) = v;
    }
}

// ---------------------------------------------------------------------------
// gemm: global-row tiling. grid 784 = 392 mt x 2 nc (nc = 256-col chunk).
// 512 thr, 8 waves (2 row x 4 col). Wave: 64 rows x 64 cols, acc[2][2] f32x16.
// BK=32, TRIPLE-buffered LDS (24 KiB each):
//   A: reg-staged fp32->bf16 (issued one tile early, written after barrier)
//   B: global_load_lds from pre-packed Wpack
// Counted s_waitcnt vmcnt(4) before each raw s_barrier -> next tile's 4 loads
// stay in flight across the barrier (never drain to 0 mid-loop).
// Epilogue: relu(acc+att2)·w_full -> per-row score partials -> spart[nc][row].
// ---------------------------------------------------------------------------
__global__ __launch_bounds__(512, 2) void bahdanau_gemm(
    const float* __restrict__ enc, const float* __restrict__ w_full,
    const float* __restrict__ att2pb, const short* __restrict__ Wpack,
    float* __restrict__ spart)
{
    // 3 bufs x (A 4096 shorts + B 8192 shorts) = 36864 shorts = 72 KiB
    __shared__ __align__(16) short lds_s[3 * 12288];
    __shared__ float redm[4][128];

    const int wg  = blockIdx.x;
    const int swz = (wg & 7) * 98 + (wg >> 3);      // 784 = 8*98, bijective
    const int mt  = swz >> 1;
    const int nc  = swz & 1;

    const int tid  = threadIdx.x;
    const int lane = tid & 63;
    const int wid  = tid >> 6;
    const int wm   = wid >> 2;       // 0..1 row-group
    const int wn   = wid & 3;        // 0..3 col-group

    // ---- A staging map: chunk ca=tid -> (rt=ca>>7, kk=(ca>>6)&1, l=ca&63)
    //      row = rt*32 + (l&31), k-offset = kk*16 + (l>>5)*8
    const int ca    = tid;
    const int arow  = ((ca >> 7) << 5) + (ca & 31);
    const int akoff = (((ca >> 6) & 1) << 4) + (((ca >> 5) & 1) << 3);
    const float* aSrc = enc + (size_t)(mt * 128 + arow) * ENC_DIM + akoff;
    short* aDst = lds_s + ca * 8;    // + buf*12288

    // ---- B staging map: two chunks cb = tid, tid+512
    //      global chunk = ((nc*8 + (cb>>7))*128 + (cb>>6)&1)*64 + (cb&63), +t*128/tile
    const int cb0 = tid, cb1 = tid + 512;
    const short* bg0 = Wpack + (size_t)(((nc * 8 + (cb0 >> 7)) * 128 + ((cb0 >> 6) & 1)) * 64 + (cb0 & 63)) * 8;
    const short* bg1 = Wpack + (size_t)(((nc * 8 + (cb1 >> 7)) * 128 + ((cb1 >> 6) & 1)) * 64 + (cb1 & 63)) * 8;

    f32x16 acc[2][2];
    #pragma unroll
    for (int i = 0; i < 2; ++i)
        #pragma unroll
        for (int j = 0; j < 2; ++j)
            #pragma unroll
            for (int r = 0; r < 16; ++r) acc[i][j][r] = 0.f;

    auto stageB = [&](int t, int buf) {
        short* lb = lds_s + buf * 12288 + 4096;
        __builtin_amdgcn_global_load_lds((gu32*)(bg0 + (size_t)t * 1024),
                                         (lu32*)(lb + cb0 * 8), 16, 0, 0);
        __builtin_amdgcn_global_load_lds((gu32*)(bg1 + (size_t)t * 1024),
                                         (lu32*)(lb + cb1 * 8), 16, 0, 0);
    };
    auto writeA = [&](int buf, float4 v0, float4 v1) {
        short8 w;
        w[0] = f2bf(v0.x); w[1] = f2bf(v0.y); w[2] = f2bf(v0.z); w[3] = f2bf(v0.w);
        w[4] = f2bf(v1.x); w[5] = f2bf(v1.y); w[6] = f2bf(v1.z); w[7] = f2bf(v1.w);
        *reinterpret_cast<short8*>(aDst + buf * 12288) = w;
    };

    // ---- prologue: A(0),B(0),A(1),B(1) in flight; buf0 fully staged
    float4 a0, a1;
    {
        const float4* p0 = reinterpret_cast<const float4*>(aSrc);
        float4 t0 = p0[0], t1 = p0[1];
        stageB(0, 0);
        const float4* p1 = reinterpret_cast<const float4*>(aSrc + 32);
        a0 = p1[0]; a1 = p1[1];
        stageB(1, 1);
        writeA(0, t0, t1);                           // compiler waits t0,t1
        asm volatile("s_waitcnt vmcnt(4) lgkmcnt(0)" ::: "memory");  // B(0) done
        __builtin_amdgcn_s_barrier();
    }

    int bc = 0, bn = 1, bn2 = 2;
    for (int t = 0; t < NTILES; ++t) {
        if (t < NTILES - 1) writeA(bn, a0, a1);      // A(t+1) -> buf(t+1)
        if (t < NTILES - 2) {
            const float4* p = reinterpret_cast<const float4*>(aSrc + (t + 2) * 32);
            a0 = p[0]; a1 = p[1];                    // A(t+2) in flight
            stageB(t + 2, bn2);                      // B(t+2) in flight
        }
        // ---- compute tile t from buf bc
        {
            const short* bA = lds_s + bc * 12288;
            const short* bB = bA + 4096;
            #pragma unroll
            for (int kk = 0; kk < 2; ++kk) {
                short8 af0 = *reinterpret_cast<const short8*>(bA + (((wm * 2 + 0) * 2 + kk) * 64 + lane) * 8);
                short8 af1 = *reinterpret_cast<const short8*>(bA + (((wm * 2 + 1) * 2 + kk) * 64 + lane) * 8);
                short8 bf0 = *reinterpret_cast<const short8*>(bB + (((wn * 2 + 0) * 2 + kk) * 64 + lane) * 8);
                short8 bf1 = *reinterpret_cast<const short8*>(bB + (((wn * 2 + 1) * 2 + kk) * 64 + lane) * 8);
                __builtin_amdgcn_s_setprio(1);
                acc[0][0] = __builtin_amdgcn_mfma_f32_32x32x16_bf16(af0, bf0, acc[0][0], 0, 0, 0);
                acc[0][1] = __builtin_amdgcn_mfma_f32_32x32x16_bf16(af0, bf1, acc[0][1], 0, 0, 0);
                acc[1][0] = __builtin_amdgcn_mfma_f32_32x32x16_bf16(af1, bf0, acc[1][0], 0, 0, 0);
                acc[1][1] = __builtin_amdgcn_mfma_f32_32x32x16_bf16(af1, bf1, acc[1][1], 0, 0, 0);
                __builtin_amdgcn_s_setprio(0);
            }
        }
        if (t < NTILES - 1) {
            if (t < NTILES - 2)
                asm volatile("s_waitcnt vmcnt(4) lgkmcnt(0)" ::: "memory");  // B(t+1) done, 4 newest fly on
            else
                asm volatile("s_waitcnt vmcnt(0) lgkmcnt(0)" ::: "memory");  // last B must land
            __builtin_amdgcn_s_barrier();
        }
        int tmp = bc; bc = bn; bn = bn2; bn2 = tmp;
    }

    // ---- epilogue: relu(att1 + att2)·w_full, reduce over cols
    float sp0[16], sp1[16];
    #pragma unroll
    for (int r = 0; r < 16; ++r) { sp0[r] = 0.f; sp1[r] = 0.f; }
    #pragma unroll
    for (int j = 0; j < 2; ++j) {
        int col  = nc * 256 + (wn * 2 + j) * 32 + (lane & 31);
        float wf = w_full[col];
        const float* a2 = att2pb + col;
        #pragma unroll
        for (int r = 0; r < 16; ++r) {
            int rit  = (r & 3) + 8 * (r >> 2) + 4 * (lane >> 5);
            int row0 = mt * 128 + (wm * 2 + 0) * 32 + rit;
            int row1 = row0 + 32;
            float v0 = acc[0][j][r] + a2[(row0 / NPIX) * ATT_DIM];
            float v1 = acc[1][j][r] + a2[(row1 / NPIX) * ATT_DIM];
            sp0[r] += fmaxf(v0, 0.f) * wf;
            sp1[r] += fmaxf(v1, 0.f) * wf;
        }
    }
    #pragma unroll
    for (int r = 0; r < 16; ++r) {
        float v0 = sp0[r], v1 = sp1[r];
        #pragma unroll
        for (int d = 1; d <= 16; d <<= 1) {
            v0 += __shfl_xor(v0, d);
            v1 += __shfl_xor(v1, d);
        }
        sp0[r] = v0; sp1[r] = v1;
    }
    if ((lane & 31) == 0) {
        #pragma unroll
        for (int r = 0; r < 16; ++r) {
            int rit = (r & 3) + 8 * (r >> 2) + 4 * (lane >> 5);
            redm[wn][(wm * 2 + 0) * 32 + rit] = sp0[r];
            redm[wn][(wm * 2 + 1) * 32 + rit] = sp1[r];
        }
    }
    __syncthreads();
    if (tid < 128)
        spart[(size_t)nc * MROWS + mt * 128 + tid] =
            redm[0][tid] + redm[1][tid] + redm[2][tid] + redm[3][tid];
}

// ---------------------------------------------------------------------------
// ctx: grid 256. Combine nc score partials, softmax (b_full invariant),
// write alpha, stream context: thread -> one float4 column, 196-pixel loop.
// ---------------------------------------------------------------------------
__global__ __launch_bounds__(512) void bahdanau_ctx(
    const float* __restrict__ enc, const float* __restrict__ spart,
    float* __restrict__ out_ctx, float* __restrict__ out_alpha)
{
    __shared__ float al[256];
    __shared__ float msum[2];
    const int b    = blockIdx.x;
    const int tid  = threadIdx.x;
    const int lane = tid & 63;
    const int wid  = tid >> 6;

    if (tid < NPIX) {
        int row = b * NPIX + tid;
        al[tid] = spart[row] + spart[MROWS + row];
    } else if (tid < 256) {
        al[tid] = -3.4e38f;
    }
    __syncthreads();

    if (wid == 0) {
        float s0 = al[lane], s1 = al[lane + 64], s2 = al[lane + 128], s3 = al[lane + 192];
        float m = fmaxf(fmaxf(s0, s1), fmaxf(s2, s3));
        #pragma unroll
        for (int d = 1; d <= 32; d <<= 1) m = fmaxf(m, __shfl_xor(m, d));
        float e = __expf(s0 - m) + __expf(s1 - m) + __expf(s2 - m) + __expf(s3 - m);
        #pragma unroll
        for (int d = 1; d <= 32; d <<= 1) e += __shfl_xor(e, d);
        if (lane == 0) { msum[0] = m; msum[1] = e; }
    }
    __syncthreads();
    float m    = msum[0];
    float rinv = 1.f / msum[1];
    if (tid < NPIX) {
        float a = __expf(al[tid] - m) * rinv;
        al[tid] = a;
        out_alpha[b * NPIX + tid] = a;
    }
    __syncthreads();

    float4 c4 = {0.f, 0.f, 0.f, 0.f};
    const float4* enc4 = reinterpret_cast<const float4*>(enc + (size_t)b * NPIX * ENC_DIM);
    #pragma unroll 4
    for (int p = 0; p < NPIX; ++p) {
        float a  = al[p];
        float4 v = enc4[(size_t)p * (ENC_DIM / 4) + tid];
        c4.x += a * v.x; c4.y += a * v.y; c4.z += a * v.z; c4.w += a * v.w;
    }
    reinterpret_cast<float4*>(out_ctx)[(size_t)b * (ENC_DIM / 4) + tid] = c4;
}

extern "C" void kernel_launch(void* const* d_in, const int* in_sizes, int n_in,
                              void* d_out, int out_size, void* d_ws, size_t ws_size,
                              hipStream_t stream) {
    const float* enc    = (const float*)d_in[0];
    const float* dech   = (const float*)d_in[1];
    const float* W_enc  = (const float*)d_in[2];
    const float* b_enc  = (const float*)d_in[3];
    const float* W_dec  = (const float*)d_in[4];
    const float* b_dec  = (const float*)d_in[5];
    const float* w_full = (const float*)d_in[6];
    // d_in[7] = b_full: softmax-invariant, unused.

    float* att2pb = (float*)d_ws;                              // 512 KiB
    short* Wpack  = (short*)((char*)d_ws + 512 * 1024);        // 2 MiB
    float* spart  = (float*)((char*)d_ws + 2560 * 1024);       // 2*50176*4 = 392 KiB

    float* out_ctx   = (float*)d_out;
    float* out_alpha = out_ctx + (size_t)BATCH * ENC_DIM;

    bahdanau_prep<<<768, 256, 0, stream>>>(dech, W_enc, b_enc, W_dec, b_dec, att2pb, Wpack);
    bahdanau_gemm<<<784, 512, 0, stream>>>(enc, w_full, att2pb, Wpack, spart);
    bahdanau_ctx<<<BATCH, 512, 0, stream>>>(enc, spart, out_ctx, out_alpha);
}

// Round 4
// 425.778 us; speedup vs baseline: 1.1482x; 1.1482x over previous
//
#include <hip/hip_runtime.h>
#include <hip/hip_bf16.h>

#define ENC_DIM 2048
#define DEC_DIM 512
#define ATT_DIM 512
#define BATCH   256
#define NPIX    196
#define MROWS   (BATCH * NPIX)          // 50176 = 392 * 128
#define KT_N    64                      // K tiles of 32

typedef __attribute__((ext_vector_type(8)))  short short8;
typedef __attribute__((ext_vector_type(4)))  float f32x4;

typedef const __attribute__((address_space(1))) unsigned int gu32;
typedef __attribute__((address_space(3))) unsigned int lu32;

__device__ __forceinline__ short f2bf(float x) {
    unsigned u = __builtin_bit_cast(unsigned, x);
    unsigned r = (u + 0x7FFFu + ((u >> 16) & 1u)) >> 16;
    return (short)r;
}
__device__ __forceinline__ unsigned pkbf(float a, float b) {
    unsigned r;
    asm("v_cvt_pk_bf16_f32 %0, %1, %2" : "=v"(r) : "v"(a), "v"(b));
    return r;
}

// ---------------------------------------------------------------------------
// prep: blocks [0,256)   -> att2pb[b][a] = b_enc[a] + b_dec[a] + h[b]·W_dec[:,a]
//       blocks [256,768) -> pack W_enc into bf16 16x16x32 B-fragment order:
//         chunk c = (nt*64 + kt)*64 + l  (nt: 16-col tile, kt: 32-K tile)
//         elem j = W_enc[kt*32 + ((l>>4)&3)*8 + j][nt*16 + (l&15)]
// ---------------------------------------------------------------------------
__global__ __launch_bounds__(256) void bahdanau_prep(
    const float* __restrict__ dec_h, const float* __restrict__ W_enc,
    const float* __restrict__ b_enc, const float* __restrict__ W_dec,
    const float* __restrict__ b_dec,
    float* __restrict__ att2pb, short* __restrict__ Wpack)
{
    int blk = blockIdx.x;
    if (blk < BATCH) {
        __shared__ float hs[DEC_DIM];
        int b = blk;
        for (int i = threadIdx.x; i < DEC_DIM; i += 256) hs[i] = dec_h[b * DEC_DIM + i];
        __syncthreads();
        for (int a = threadIdx.x; a < ATT_DIM; a += 256) {
            float s = 0.f;
            #pragma unroll 8
            for (int d = 0; d < DEC_DIM; ++d) s += hs[d] * W_dec[d * ATT_DIM + a];
            att2pb[b * ATT_DIM + a] = s + b_dec[a] + b_enc[a];
        }
    } else {
        int c  = (blk - BATCH) * 256 + threadIdx.x;   // 0 .. 131071
        int l  = c & 63;
        int kt = (c >> 6) & 63;
        int nt = c >> 12;
        int n     = nt * 16 + (l & 15);
        int kbase = kt * 32 + ((l >> 4) & 3) * 8;
        short8 v;
        #pragma unroll
        for (int j = 0; j < 8; ++j) v[j] = f2bf(W_enc[(kbase + j) * ATT_DIM + n]);
        *reinterpret_cast<short8*>(Wpack + (size_t)c * 8) = v;
    }
}

// ---------------------------------------------------------------------------
// gemm: m97-style. grid 1568 = 392 mt x 4 nc; 256 thr, 4 waves (2 wm x 2 wn).
// Tile 128 rows x 128 cols; wave: 64x64 = 4x4 frags of 16x16x32, acc 64 regs.
// LDS per buf: A fp32 128x32 (16 KB, K-quad XOR-swizzled via inverse-swizzled
// global source, rule #21) + B bf16 frag-order (8 KB). Double-buffered,
// global_load_lds w=16 for both, ONE __syncthreads per K-step (T3 minimum:
// stage(next) issued before compute(cur), drained by the barrier after).
// A frags converted fp32->bf16 post-ds_read via v_cvt_pk_bf16_f32.
// Epilogue folds relu(att1+att2)·w_full -> spart[nc][row].
// ---------------------------------------------------------------------------
__global__ __launch_bounds__(256) void bahdanau_gemm(
    const float* __restrict__ enc, const float* __restrict__ w_full,
    const float* __restrict__ att2pb, const short* __restrict__ Wpack,
    float* __restrict__ spart)
{
    __shared__ __align__(16) char lds[2 * 24576];   // buf: A 16K + B 8K
    __shared__ float redm[2][128];

    const int wg = blockIdx.x;                      // 1568 = 49*32
    const int mt = ((wg >> 5) << 3) | (wg & 7);     // same-mt blocks -> same XCD
    const int nc = (wg >> 3) & 3;

    const int tid  = threadIdx.x;
    const int lane = tid & 63;
    const int wid  = tid >> 6;
    const int wm   = wid >> 1;                      // row half
    const int wn   = wid & 1;                       // col half

    // ---- A staging source offsets (element units), chunk i = tid + 256*s
    //      r = i>>3, qq = i&7 ; src k-quad = qq ^ (r&7)  (inverse swizzle)
    size_t aoff[4];
    #pragma unroll
    for (int s = 0; s < 4; ++s) {
        int i = tid + 256 * s, r = i >> 3, qq = i & 7;
        aoff[s] = (size_t)(mt * 128 + r) * ENC_DIM + ((qq ^ (r & 7)) << 2);
    }
    // ---- B staging source (short units), chunk i = tid + 256*s, f=i>>6, ln=i&63
    size_t boff[2];
    #pragma unroll
    for (int s = 0; s < 2; ++s) {
        int i = tid + 256 * s, f = i >> 6, ln = i & 63;
        boff[s] = ((size_t)(nc * 8 + f) * 64 * 64 + ln) * 8;   // + kt*512
    }

    f32x4 acc[4][4];
    #pragma unroll
    for (int a = 0; a < 4; ++a)
        #pragma unroll
        for (int c = 0; c < 4; ++c)
            #pragma unroll
            for (int r = 0; r < 4; ++r) acc[a][c][r] = 0.f;

    auto STAGE = [&](int buf, int kt) {
        char* ab = lds + buf * 24576;
        char* bb = ab + 16384;
        #pragma unroll
        for (int s = 0; s < 4; ++s)
            __builtin_amdgcn_global_load_lds((gu32*)(enc + aoff[s] + kt * 32),
                                             (lu32*)(ab + (tid + 256 * s) * 16), 16, 0, 0);
        #pragma unroll
        for (int s = 0; s < 2; ++s)
            __builtin_amdgcn_global_load_lds((gu32*)(Wpack + boff[s] + (size_t)kt * 512),
                                             (lu32*)(bb + (tid + 256 * s) * 16), 16, 0, 0);
    };

    auto COMPUTE = [&](int buf) {
        const char* ab = lds + buf * 24576;
        const char* bb = ab + 16384;
        short8 af[4], bf[4];
        #pragma unroll
        for (int rt = 0; rt < 4; ++rt) {
            int r  = wm * 64 + rt * 16 + (lane & 15);
            int q0 = ((lane >> 4) & 3) * 2;
            float4 lo = *reinterpret_cast<const float4*>(ab + r * 128 + ((q0       ^ (r & 7)) << 4));
            float4 hi = *reinterpret_cast<const float4*>(ab + r * 128 + (((q0 + 1) ^ (r & 7)) << 4));
            union { short8 s; unsigned u[4]; } fr;
            fr.u[0] = pkbf(lo.x, lo.y); fr.u[1] = pkbf(lo.z, lo.w);
            fr.u[2] = pkbf(hi.x, hi.y); fr.u[3] = pkbf(hi.z, hi.w);
            af[rt] = fr.s;
        }
        #pragma unroll
        for (int ct = 0; ct < 4; ++ct)
            bf[ct] = *reinterpret_cast<const short8*>(bb + (wn * 4 + ct) * 1024 + lane * 16);
        #pragma unroll
        for (int rt = 0; rt < 4; ++rt)
            #pragma unroll
            for (int ct = 0; ct < 4; ++ct)
                acc[rt][ct] = __builtin_amdgcn_mfma_f32_16x16x32_bf16(af[rt], bf[ct], acc[rt][ct], 0, 0, 0);
    };

    STAGE(0, 0);
    __syncthreads();
    for (int kt2 = 0; kt2 < KT_N; kt2 += 2) {
        STAGE(1, kt2 + 1);                 // always valid: kt2+1 <= 63
        COMPUTE(0);
        __syncthreads();
        if (kt2 + 2 < KT_N) STAGE(0, kt2 + 2);
        COMPUTE(1);
        __syncthreads();
    }

    // ---- epilogue: relu(att1 + att2)·w_full -> per-row partials over 64 cols
    float srow[16];
    #pragma unroll
    for (int i = 0; i < 16; ++i) srow[i] = 0.f;
    #pragma unroll
    for (int ct = 0; ct < 4; ++ct) {
        int col  = nc * 128 + wn * 64 + ct * 16 + (lane & 15);
        float wf = w_full[col];
        #pragma unroll
        for (int rt = 0; rt < 4; ++rt) {
            #pragma unroll
            for (int r = 0; r < 4; ++r) {
                unsigned grow = mt * 128 + wm * 64 + rt * 16 + ((lane >> 4) & 3) * 4 + r;
                unsigned bb   = grow / NPIX;
                float v = acc[rt][ct][r] + att2pb[bb * ATT_DIM + col];
                srow[rt * 4 + r] += fmaxf(v, 0.f) * wf;
            }
        }
    }
    #pragma unroll
    for (int i = 0; i < 16; ++i) {
        float v = srow[i];
        v += __shfl_xor(v, 1);
        v += __shfl_xor(v, 2);
        v += __shfl_xor(v, 4);
        v += __shfl_xor(v, 8);
        srow[i] = v;
    }
    if ((lane & 15) == 0) {
        #pragma unroll
        for (int rt = 0; rt < 4; ++rt)
            #pragma unroll
            for (int r = 0; r < 4; ++r)
                redm[wn][wm * 64 + rt * 16 + ((lane >> 4) & 3) * 4 + r] = srow[rt * 4 + r];
    }
    __syncthreads();
    if (tid < 128)
        spart[(size_t)nc * MROWS + mt * 128 + tid] = redm[0][tid] + redm[1][tid];
}

// ---------------------------------------------------------------------------
// ctx: grid 256. Sum 4 nc score partials, softmax (b_full invariant),
// write alpha, stream context: thread -> one float4 column, 196-pixel loop.
// ---------------------------------------------------------------------------
__global__ __launch_bounds__(512) void bahdanau_ctx(
    const float* __restrict__ enc, const float* __restrict__ spart,
    float* __restrict__ out_ctx, float* __restrict__ out_alpha)
{
    __shared__ float al[256];
    __shared__ float msum[2];
    const int b    = blockIdx.x;
    const int tid  = threadIdx.x;
    const int lane = tid & 63;
    const int wid  = tid >> 6;

    if (tid < NPIX) {
        int row = b * NPIX + tid;
        al[tid] = spart[row] + spart[MROWS + row] + spart[2 * MROWS + row] + spart[3 * MROWS + row];
    } else if (tid < 256) {
        al[tid] = -3.4e38f;
    }
    __syncthreads();

    if (wid == 0) {
        float s0 = al[lane], s1 = al[lane + 64], s2 = al[lane + 128], s3 = al[lane + 192];
        float m = fmaxf(fmaxf(s0, s1), fmaxf(s2, s3));
        #pragma unroll
        for (int d = 1; d <= 32; d <<= 1) m = fmaxf(m, __shfl_xor(m, d));
        float e = __expf(s0 - m) + __expf(s1 - m) + __expf(s2 - m) + __expf(s3 - m);
        #pragma unroll
        for (int d = 1; d <= 32; d <<= 1) e += __shfl_xor(e, d);
        if (lane == 0) { msum[0] = m; msum[1] = e; }
    }
    __syncthreads();
    float m    = msum[0];
    float rinv = 1.f / msum[1];
    if (tid < NPIX) {
        float a = __expf(al[tid] - m) * rinv;
        al[tid] = a;
        out_alpha[b * NPIX + tid] = a;
    }
    __syncthreads();

    float4 c4 = {0.f, 0.f, 0.f, 0.f};
    const float4* enc4 = reinterpret_cast<const float4*>(enc + (size_t)b * NPIX * ENC_DIM);
    #pragma unroll 4
    for (int p = 0; p < NPIX; ++p) {
        float a  = al[p];
        float4 v = enc4[(size_t)p * (ENC_DIM / 4) + tid];
        c4.x += a * v.x; c4.y += a * v.y; c4.z += a * v.z; c4.w += a * v.w;
    }
    reinterpret_cast<float4*>(out_ctx)[(size_t)b * (ENC_DIM / 4) + tid] = c4;
}

extern "C" void kernel_launch(void* const* d_in, const int* in_sizes, int n_in,
                              void* d_out, int out_size, void* d_ws, size_t ws_size,
                              hipStream_t stream) {
    const float* enc    = (const float*)d_in[0];
    const float* dech   = (const float*)d_in[1];
    const float* W_enc  = (const float*)d_in[2];
    const float* b_enc  = (const float*)d_in[3];
    const float* W_dec  = (const float*)d_in[4];
    const float* b_dec  = (const float*)d_in[5];
    const float* w_full = (const float*)d_in[6];
    // d_in[7] = b_full: softmax-invariant, unused.

    float* att2pb = (float*)d_ws;                              // 512 KiB
    short* Wpack  = (short*)((char*)d_ws + 512 * 1024);        // 2 MiB
    float* spart  = (float*)((char*)d_ws + 2560 * 1024);       // 4*50176*4 = 784 KiB

    float* out_ctx   = (float*)d_out;
    float* out_alpha = out_ctx + (size_t)BATCH * ENC_DIM;

    bahdanau_prep<<<768, 256, 0, stream>>>(dech, W_enc, b_enc, W_dec, b_dec, att2pb, Wpack);
    bahdanau_gemm<<<1568, 256, 0, stream>>>(enc, w_full, att2pb, Wpack, spart);
    bahdanau_ctx<<<BATCH, 512, 0, stream>>>(enc, spart, out_ctx, out_alpha);
}